// Round 10
// baseline (159.817 us; speedup 1.0000x reference)
//
#include <hip/hip_runtime.h>

typedef short s16x4 __attribute__((ext_vector_type(4)));
typedef short s16x8 __attribute__((ext_vector_type(8)));
typedef float f32x4 __attribute__((ext_vector_type(4)));
typedef unsigned int u32;

#define DEV static __device__ __forceinline__

// B=4, S=2048, D=512, H=8, DK=64, M = B*S = 8192

DEV unsigned short f2bf(float f) {
    unsigned u = __float_as_uint(f);
    u += 0x7FFFu + ((u >> 16) & 1u);   // RNE round to bf16
    return (unsigned short)(u >> 16);
}

DEV u32 cvtpk(float lo, float hi) {
    u32 r;
    asm("v_cvt_pk_bf16_f32 %0, %1, %2" : "=v"(r) : "v"(lo), "v"(hi));
    return r;
}
DEV void pl32swap(u32& a, u32& b) {
    asm("v_permlane32_swap_b32 %0, %1" : "+v"(a), "+v"(b));
}
DEV void pl16swap(u32& a, u32& b) {
    asm("v_permlane16_swap_b32 %0, %1" : "+v"(a), "+v"(b));
}
DEV void gl16(const void* g, void* l) {
    __builtin_amdgcn_global_load_lds((const __attribute__((address_space(1))) u32*)g,
                                     (__attribute__((address_space(3))) u32*)l, 16, 0, 0);
}

// ---------------- fused LayerNorm + weight convert ----------------
__global__ __launch_bounds__(256) void lnw_kernel(const float* __restrict__ x,
        const float* __restrict__ gamma, const float* __restrict__ beta,
        unsigned short* __restrict__ xn,
        const float* __restrict__ wq, const float* __restrict__ wk,
        const float* __restrict__ wv, const float* __restrict__ wo,
        unsigned short* __restrict__ wdst)
{
    if (blockIdx.x >= 2048) {
        int idx = blockIdx.x - 2048;
        int m = idx >> 6, sub = idx & 63;
        const float* src = (m == 0) ? wq : (m == 1) ? wk : (m == 2) ? wv : wo;
        unsigned short* d = wdst + (size_t)m * 262144;
        const f32x4* s4 = (const f32x4*)src;
        s16x4* d4 = (s16x4*)d;
#pragma unroll
        for (int i = 0; i < 4; ++i) {
            int e = sub * 1024 + i * 256 + threadIdx.x;
            f32x4 v = s4[e];
            s16x4 o;
            o[0] = f2bf(v[0]); o[1] = f2bf(v[1]); o[2] = f2bf(v[2]); o[3] = f2bf(v[3]);
            d4[e] = o;
        }
        return;
    }
    int t = threadIdx.x, w = t >> 6, lane = t & 63;
    int row = blockIdx.x * 4 + w;
    const float* xr = x + (size_t)row * 512 + lane * 8;
    f32x4 v0 = *(const f32x4*)xr;
    f32x4 v1 = *(const f32x4*)(xr + 4);
    float s = 0.f, s2 = 0.f;
#pragma unroll
    for (int i = 0; i < 4; ++i) { s += v0[i] + v1[i]; s2 += v0[i] * v0[i] + v1[i] * v1[i]; }
#pragma unroll
    for (int m = 1; m < 64; m <<= 1) { s += __shfl_xor(s, m); s2 += __shfl_xor(s2, m); }
    float mu = s * (1.f / 512.f);
    float var = s2 * (1.f / 512.f) - mu * mu;
    float rstd = rsqrtf(var + 1e-5f);
    f32x4 g0 = *(const f32x4*)(gamma + lane * 8);
    f32x4 g1 = *(const f32x4*)(gamma + lane * 8 + 4);
    f32x4 b0 = *(const f32x4*)(beta + lane * 8);
    f32x4 b1 = *(const f32x4*)(beta + lane * 8 + 4);
    s16x8 o;
#pragma unroll
    for (int i = 0; i < 4; ++i) {
        o[i]     = f2bf((v0[i] - mu) * rstd * g0[i] + b0[i]);
        o[i + 4] = f2bf((v1[i] - mu) * rstd * g1[i] + b1[i]);
    }
    *(s16x8*)(xn + (size_t)row * 512 + lane * 8) = o;
}

// ---------------- pipelined 128x128 GEMM core (BK=32, 3-buf, depth-2 prefetch) ----------------
#define GEMM_PIPE(APTR, BPTR, ACC) do { \
    int bc_ = 0, bs_ = 2; \
    STAGE(0, 0); STAGE(1, 1); \
    for (int it_ = 0; it_ < 16; ++it_) { \
        asm volatile("" ::: "memory"); \
        __builtin_amdgcn_s_barrier(); \
        if (it_ + 2 < 16) { \
            STAGE(it_ + 2, bs_); \
            asm volatile("s_waitcnt vmcnt(8)" ::: "memory"); \
        } else if (it_ + 1 < 16) { \
            asm volatile("s_waitcnt vmcnt(4)" ::: "memory"); \
        } else { \
            asm volatile("s_waitcnt vmcnt(0)" ::: "memory"); \
        } \
        __builtin_amdgcn_s_barrier(); \
        asm volatile("" ::: "memory"); \
        const char* Ab_ = (const char*)(APTR) + bc_ * 8192; \
        const char* Bb_ = (const char*)(BPTR) + bc_ * 8192; \
        s16x8 af_[4], bf_[4]; \
        _Pragma("unroll") \
        for (int i_ = 0; i_ < 4; ++i_) { \
            af_[i_] = *(const s16x8*)(Ab_ + (wm * 64 + i_ * 16 + l15) * 64 + swz); \
            bf_[i_] = *(const s16x8*)(Bb_ + (wn * 64 + i_ * 16 + l15) * 64 + swz); \
        } \
        __builtin_amdgcn_s_setprio(1); \
        _Pragma("unroll") \
        for (int i_ = 0; i_ < 4; ++i_) \
            _Pragma("unroll") \
            for (int j_ = 0; j_ < 4; ++j_) \
                ACC[i_][j_] = __builtin_amdgcn_mfma_f32_16x16x32_bf16(af_[i_], bf_[j_], ACC[i_][j_], 0, 0, 0); \
        __builtin_amdgcn_s_setprio(0); \
        bc_ = (bc_ == 2) ? 0 : bc_ + 1; \
        bs_ = (bs_ == 2) ? 0 : bs_ + 1; \
    } \
} while (0)

// ---------------- QKV projection GEMM ----------------
// z=0 -> q (b,h,s,dk) scaled 0.125*log2e ; z=1 -> K frag-major ; z=2 -> V frag-major
__global__ __launch_bounds__(256, 3) void qkv_kernel(const unsigned short* __restrict__ xn,
        const unsigned short* __restrict__ wbase,
        const float* __restrict__ bq, const float* __restrict__ bk, const float* __restrict__ bv,
        unsigned short* __restrict__ qo, unsigned short* __restrict__ kfm,
        unsigned short* __restrict__ vfm)
{
    __shared__ __align__(16) unsigned short As[3][128 * 32];
    __shared__ __align__(16) unsigned short Bs[3][128 * 32];
    int z = blockIdx.z;
    const unsigned short* W = wbase + (size_t)z * 262144;
    const float* bias = (z == 0) ? bq : (z == 1) ? bk : bv;

    int t = threadIdx.x, lane = t & 63, w = t >> 6;
    int g = lane >> 4, l15 = lane & 15;
    int wm = w >> 1, wn = w & 1;
    int mBase = blockIdx.x * 128, nBase = blockIdx.y * 128;

    int srow = t >> 2;
    int scol = ((t & 3) ^ ((t >> 2) & 3) ^ ((t >> 4) & 3)) * 8;
    const unsigned short* ag = xn + (size_t)(mBase + srow) * 512 + scol;
    const unsigned short* bg = W + (size_t)(nBase + srow) * 512 + scol;
    int swz = ((g ^ (l15 & 3) ^ ((l15 >> 2) & 3))) * 16;

    f32x4 acc[4][4] = {};

#define STAGE(it_, buf_) do { \
        int k0_ = (it_) * 32; \
        gl16(ag + k0_,          (char*)&As[buf_][0] + t * 16); \
        gl16(ag + 32768 + k0_,  (char*)&As[buf_][0] + t * 16 + 4096); \
        gl16(bg + k0_,          (char*)&Bs[buf_][0] + t * 16); \
        gl16(bg + 32768 + k0_,  (char*)&Bs[buf_][0] + t * 16 + 4096); \
    } while (0)

    GEMM_PIPE(&As[0][0], &Bs[0][0], acc);
#undef STAGE

#pragma unroll
    for (int i = 0; i < 4; ++i) {
        int row0 = mBase + wm * 64 + i * 16 + g * 4;
        int bb = row0 >> 11;
        int s0 = row0 & 2047;
#pragma unroll
        for (int j = 0; j < 4; ++j) {
            int col = nBase + wn * 64 + j * 16 + l15;
            float bia = bias[col];
            int h = col >> 6, dk = col & 63;
            int bh = bb * 8 + h;
            if (z == 0) {
                float sc = 0.18033688011112042f;   // 0.125*log2(e)
#pragma unroll
                for (int r = 0; r < 4; ++r)
                    qo[((size_t)bh * 2048 + (s0 + r)) * 64 + dk] = f2bf((acc[i][j][r] + bia) * sc);
            } else if (z == 1) {
                int ks = dk >> 5, gg = (dk >> 3) & 3, e = dk & 7;
                int tile = s0 >> 6, kf = (s0 >> 4) & 3, l0 = s0 & 15;
                size_t base = ((size_t)bh * 32 + tile) * 4096 + (kf * 2 + ks) * 512 + (gg * 16 + l0) * 8 + e;
#pragma unroll
                for (int r = 0; r < 4; ++r)
                    kfm[base + r * 8] = f2bf(acc[i][j][r] + bia);
            } else {
                int nf = dk >> 4, l0v = dk & 15;
                int tile = s0 >> 6, half = (s0 >> 5) & 1, gg = (s0 >> 3) & 3, e0 = s0 & 7;
                size_t base = ((size_t)bh * 32 + tile) * 4096 + (nf * 2 + half) * 512 + (gg * 16 + l0v) * 8 + e0;
                s16x4 pk;
#pragma unroll
                for (int r = 0; r < 4; ++r) pk[r] = f2bf(acc[i][j][r] + bia);
                *(s16x4*)(vfm + base) = pk;
            }
        }
    }
}

// ---------------- flash attention: K reg-prefetch depth-1, V-only LDS, 1 barrier/tile ----------------
// grid 1024, 256 thr = 4 waves x 32 q (128 q/block), KV-split-2.
// ka(t+1) issued AFTER QK^T(t) (loop-carried regs): the compiler wait before
// QK^T(t+1) then retires loads issued a full softmax+PV earlier -> L2 latency hidden.
// Queue before barrier: [V(t+1):2][ka(t):8][V(t+2):2] = 12 -> vmcnt constants 12/10/8 unchanged.
__global__ __launch_bounds__(256, 4) void attn_kernel(const unsigned short* __restrict__ q,
        const unsigned short* __restrict__ kfm, const unsigned short* __restrict__ vfm,
        const int* __restrict__ lens, unsigned short* __restrict__ o_part, float* __restrict__ l_part)
{
    __shared__ __align__(16) unsigned short Vts[4][4096];   // [buf][8 frags][512 elems]

    int t = threadIdx.x, lane = t & 63, w = t >> 6;
    int g = lane >> 4, l15 = lane & 15;
    int lin = blockIdx.x;
    int bh = lin & 31;
    int rest = lin >> 5;               // 0..31
    int split = rest & 1;
    int qt = rest >> 1;                // 0..15
    int b = bh >> 3, h = bh & 7;
    int qb = qt * 128 + w * 32;
    int len = lens[b];
    int ntf = (len + 63) >> 6;
    int nt0 = (ntf + 1) >> 1;
    int tbeg = split ? nt0 : 0;
    int ntX = (split ? ntf : nt0) - tbeg;

    const unsigned short* kbh = kfm + (size_t)bh * 131072;
    const unsigned short* vbh = vfm + (size_t)bh * 131072;

    s16x8 qf_[2][2];
#pragma unroll
    for (int qf = 0; qf < 2; ++qf)
#pragma unroll
        for (int ks = 0; ks < 2; ++ks)
            qf_[qf][ks] = *(const s16x8*)(q + ((size_t)bh * 2048 + qb + qf * 16 + l15) * 64 + ks * 32 + g * 8);

    s16x8 ones;
#pragma unroll
    for (int i = 0; i < 8; ++i) ones[i] = (short)0x3F80;   // bf16 1.0

    f32x4 oacc[2][4] = {};   // [qf][nf]
    f32x4 sacc[2] = {};

#define STAGE_V(tile, buf) do { \
        const unsigned short* vp_ = vbh + (size_t)(tile) * 4096 + t * 8; \
        char* vld_ = (char*)&Vts[buf][0] + t * 16; \
        gl16(vp_, vld_); \
        gl16(vp_ + 2048, vld_ + 4096); \
    } while (0)

#define LOAD_KA(tile) do { \
        const unsigned short* kt_ = kbh + (size_t)(tile) * 4096; \
        _Pragma("unroll") \
        for (int kf_ = 0; kf_ < 4; ++kf_) \
            _Pragma("unroll") \
            for (int ks_ = 0; ks_ < 2; ++ks_) \
                ka[kf_][ks_] = *(const s16x8*)(kt_ + ((kf_ & 1) * 2 + ks_) * 512 + (kf_ >> 1) * 2048 + lane * 8); \
    } while (0)

    STAGE_V(tbeg, 0);
    if (ntX > 1) STAGE_V(tbeg + 1, 1);
    s16x8 ka[4][2];
    LOAD_KA(tbeg);

    for (int li = 0; li < ntX; ++li) {
        int tt = tbeg + li;
        int kb = tt << 6;

        if (li + 2 < ntX) {
            STAGE_V(tt + 2, (li + 2) & 3);
            asm volatile("s_waitcnt vmcnt(12)" ::: "memory");   // V(li) landed; ka(li)+V(li+1)+V(li+2) in flight
        } else if (li + 1 < ntX) {
            asm volatile("s_waitcnt vmcnt(10)" ::: "memory");   // leaves V(li+1)+ka(li)
        } else {
            asm volatile("s_waitcnt vmcnt(8)" ::: "memory");    // leaves ka(li) only
        }
        __builtin_amdgcn_s_barrier();              // all waves certified V(li)
        asm volatile("" ::: "memory");

        const char* Vb = (const char*)&Vts[li & 3][0];

        // QK^T -> S^T: sa[kf2][qf]; k-row = kf2*16 + g*4 + r
        f32x4 sa[4][2] = {};
#pragma unroll
        for (int ks = 0; ks < 2; ++ks) {
            __builtin_amdgcn_s_setprio(1);
#pragma unroll
            for (int kf = 0; kf < 4; ++kf)
#pragma unroll
                for (int qf = 0; qf < 2; ++qf)
                    sa[kf][qf] = __builtin_amdgcn_mfma_f32_16x16x32_bf16(
                        ka[(kf >> 1) * 2 + (kf & 1)][ks], qf_[qf][ks], sa[kf][qf], 0, 0, 0);
            __builtin_amdgcn_s_setprio(0);
        }

        // prefetch next tile's K into the (now-dead) ka regs; consumed next iteration
        if (li + 1 < ntX) LOAD_KA(tt + 1);

        if (kb + 64 > len) {
            const float NEG = -__builtin_huge_valf();
#pragma unroll
            for (int kf = 0; kf < 4; ++kf)
#pragma unroll
                for (int r = 0; r < 4; ++r)
                    if (kb + kf * 16 + g * 4 + r >= len) { sa[kf][0][r] = NEG; sa[kf][1][r] = NEG; }
        }

        // two k-halves: exp2 (fixed-max, scale folded into q) -> permlane P -> PV
#pragma unroll
        for (int half = 0; half < 2; ++half) {
            s16x8 vbf[4];
#pragma unroll
            for (int nf = 0; nf < 4; ++nf)
                vbf[nf] = *(const s16x8*)(Vb + (nf * 2 + half) * 1024 + lane * 16);
            u32 pkd[2][2][2];
#pragma unroll
            for (int qf = 0; qf < 2; ++qf)
#pragma unroll
                for (int k2 = 0; k2 < 2; ++k2) {
                    int kf = half * 2 + k2;
#pragma unroll
                    for (int r = 0; r < 4; ++r)
                        sa[kf][qf][r] = __builtin_amdgcn_exp2f(sa[kf][qf][r]);
                    pkd[k2][qf][0] = cvtpk(sa[kf][qf][0], sa[kf][qf][1]);
                    pkd[k2][qf][1] = cvtpk(sa[kf][qf][2], sa[kf][qf][3]);
                }
            __builtin_amdgcn_s_setprio(1);
#pragma unroll
            for (int qf = 0; qf < 2; ++qf) {
                u32 a0 = pkd[0][qf][0], b0 = pkd[1][qf][0];
                u32 a1 = pkd[0][qf][1], b1 = pkd[1][qf][1];
                pl32swap(a0, b0); pl16swap(a0, b0);
                pl32swap(a1, b1); pl16swap(a1, b1);
                union { u32 d[4]; s16x8 v; } pf;
                pf.d[0] = a0; pf.d[1] = a1; pf.d[2] = b0; pf.d[3] = b1;
                sacc[qf] = __builtin_amdgcn_mfma_f32_16x16x32_bf16(pf.v, ones, sacc[qf], 0, 0, 0);
#pragma unroll
                for (int nf = 0; nf < 4; ++nf)
                    oacc[qf][nf] = __builtin_amdgcn_mfma_f32_16x16x32_bf16(pf.v, vbf[nf], oacc[qf][nf], 0, 0, 0);
            }
            __builtin_amdgcn_s_setprio(0);
        }
        asm volatile("" ::: "memory");
    }
#undef STAGE_V
#undef LOAD_KA

    // write bf16 unnormalized O partial + fp32 l partial
    unsigned short* op = o_part + (size_t)split * (8192 * 512);
#pragma unroll
    for (int qf = 0; qf < 2; ++qf)
#pragma unroll
        for (int r = 0; r < 4; ++r) {
            int s = qb + qf * 16 + g * 4 + r;
#pragma unroll
            for (int nf = 0; nf < 4; ++nf)
                op[(size_t)(b * 2048 + s) * 512 + h * 64 + nf * 16 + l15] = f2bf(oacc[qf][nf][r]);
        }
    float* lp = l_part + split * 65536 + bh * 2048;
    if (l15 == 0) {
#pragma unroll
        for (int qf = 0; qf < 2; ++qf)
#pragma unroll
            for (int r = 0; r < 4; ++r)
                lp[qb + qf * 16 + g * 4 + r] = sacc[qf][r];
    }
}

// ---------------- combine: (O0+O1)/(l0+l1) -> bf16 ----------------
__global__ __launch_bounds__(256) void comb_kernel(const unsigned short* __restrict__ o_part,
        const float* __restrict__ l_part, unsigned short* __restrict__ A)
{
    int e0 = (blockIdx.x * 256 + threadIdx.x) * 8;
    int row = e0 >> 9, col0 = e0 & 511;
    int b = row >> 11, s = row & 2047, h = col0 >> 6;
    s16x8 u0 = *(const s16x8*)(o_part + (size_t)row * 512 + col0);
    s16x8 u1 = *(const s16x8*)(o_part + (size_t)(8192 + row) * 512 + col0);
    float l = l_part[(b * 8 + h) * 2048 + s] + l_part[65536 + (b * 8 + h) * 2048 + s];
    float inv = 1.f / l;
    s16x8 o;
#pragma unroll
    for (int i = 0; i < 8; ++i) {
        float f0 = __uint_as_float(((u32)(unsigned short)u0[i]) << 16);
        float f1 = __uint_as_float(((u32)(unsigned short)u1[i]) << 16);
        o[i] = f2bf((f0 + f1) * inv);
    }
    *(s16x8*)(A + (size_t)row * 512 + col0) = o;
}

// ---------------- output projection GEMM (fp32 out) ----------------
__global__ __launch_bounds__(256, 3) void oproj_kernel(const unsigned short* __restrict__ A,
        const unsigned short* __restrict__ W, const float* __restrict__ bo,
        float* __restrict__ out)
{
    __shared__ __align__(16) unsigned short As[3][128 * 32];
    __shared__ __align__(16) unsigned short Bs[3][128 * 32];
    int t = threadIdx.x, lane = t & 63, w = t >> 6;
    int g = lane >> 4, l15 = lane & 15;
    int wm = w >> 1, wn = w & 1;
    int mBase = blockIdx.x * 128, nBase = blockIdx.y * 128;

    int srow = t >> 2;
    int scol = ((t & 3) ^ ((t >> 2) & 3) ^ ((t >> 4) & 3)) * 8;
    const unsigned short* ag = A + (size_t)(mBase + srow) * 512 + scol;
    const unsigned short* bg = W + (size_t)(nBase + srow) * 512 + scol;
    int swz = ((g ^ (l15 & 3) ^ ((l15 >> 2) & 3))) * 16;

    f32x4 acc[4][4] = {};

#define STAGE(it_, buf_) do { \
        int k0_ = (it_) * 32; \
        gl16(ag + k0_,          (char*)&As[buf_][0] + t * 16); \
        gl16(ag + 32768 + k0_,  (char*)&As[buf_][0] + t * 16 + 4096); \
        gl16(bg + k0_,          (char*)&Bs[buf_][0] + t * 16); \
        gl16(bg + 32768 + k0_,  (char*)&Bs[buf_][0] + t * 16 + 4096); \
    } while (0)

    GEMM_PIPE(&As[0][0], &Bs[0][0], acc);
#undef STAGE

#pragma unroll
    for (int i = 0; i < 4; ++i) {
        int row0 = mBase + wm * 64 + i * 16 + g * 4;
#pragma unroll
        for (int j = 0; j < 4; ++j) {
            int col = nBase + wn * 64 + j * 16 + l15;
            float bia = bo[col];
#pragma unroll
            for (int r = 0; r < 4; ++r)
                out[(size_t)(row0 + r) * 512 + col] = acc[i][j][r] + bia;
        }
    }
}

extern "C" void kernel_launch(void* const* d_in, const int* in_sizes, int n_in,
                              void* d_out, int out_size, void* d_ws, size_t ws_size,
                              hipStream_t stream) {
    (void)in_sizes; (void)n_in; (void)out_size; (void)ws_size;
    const float* x     = (const float*)d_in[0];
    const int*   lens  = (const int*)d_in[1];
    // d_in[2] = pos_embed (unused by reference)
    const float* gamma = (const float*)d_in[3];
    const float* beta  = (const float*)d_in[4];
    const float* Wq = (const float*)d_in[5];
    const float* bq = (const float*)d_in[6];
    const float* Wk = (const float*)d_in[7];
    const float* bk = (const float*)d_in[8];
    const float* Wv = (const float*)d_in[9];
    const float* bv = (const float*)d_in[10];
    const float* Wo = (const float*)d_in[11];
    const float* bo = (const float*)d_in[12];

    char* ws = (char*)d_ws;
    unsigned short* wbf = (unsigned short*)(ws);                  // 0..2MB: 4x512x512 bf16
    unsigned short* xn  = (unsigned short*)(ws + (2ull  << 20));  // 2..10MB: LN out / attn-combined (oproj A)
    unsigned short* qb_ = (unsigned short*)(ws + (10ull << 20));  // (b,h,s,dk)
    unsigned short* kfm = (unsigned short*)(ws + (18ull << 20));  // K frag-major
    unsigned short* vfm = (unsigned short*)(ws + (26ull << 20));  // V frag-major
    unsigned short* o_part = (unsigned short*)(ws + (34ull << 20)); // 34..50MB: [2][8192][512] bf16
    float* l_part = (float*)(ws + (50ull << 20));                 // 50..50.5MB: [2][32][2048] f32
    float* out = (float*)d_out;

    lnw_kernel<<<2304, 256, 0, stream>>>(x, gamma, beta, xn, Wq, Wk, Wv, Wo, wbf);
    qkv_kernel<<<dim3(64, 4, 3), 256, 0, stream>>>(xn, wbf, bq, bk, bv, qb_, kfm, vfm);
    attn_kernel<<<1024, 256, 0, stream>>>(qb_, kfm, vfm, lens, o_part, l_part);
    comb_kernel<<<2048, 256, 0, stream>>>(o_part, l_part, xn);
    oproj_kernel<<<dim3(64, 4), 256, 0, stream>>>(xn, wbf + 3 * 262144, bo, out);
}

// Round 11
// 89.313 us; speedup vs baseline: 1.7894x; 1.7894x over previous
//
#include <hip/hip_runtime.h>

typedef short s16x4 __attribute__((ext_vector_type(4)));
typedef short s16x8 __attribute__((ext_vector_type(8)));
typedef float f32x4 __attribute__((ext_vector_type(4)));
typedef unsigned int u32;

#define DEV static __device__ __forceinline__

// B=4, S=2048, D=512, H=8, DK=64, M = B*S = 8192

DEV unsigned short f2bf(float f) {
    unsigned u = __float_as_uint(f);
    u += 0x7FFFu + ((u >> 16) & 1u);   // RNE round to bf16
    return (unsigned short)(u >> 16);
}

DEV u32 cvtpk(float lo, float hi) {
    u32 r;
    asm("v_cvt_pk_bf16_f32 %0, %1, %2" : "=v"(r) : "v"(lo), "v"(hi));
    return r;
}
DEV void pl32swap(u32& a, u32& b) {
    asm("v_permlane32_swap_b32 %0, %1" : "+v"(a), "+v"(b));
}
DEV void pl16swap(u32& a, u32& b) {
    asm("v_permlane16_swap_b32 %0, %1" : "+v"(a), "+v"(b));
}
DEV void gl16(const void* g, void* l) {
    __builtin_amdgcn_global_load_lds((const __attribute__((address_space(1))) u32*)g,
                                     (__attribute__((address_space(3))) u32*)l, 16, 0, 0);
}

// ---------------- fused LayerNorm + weight convert ----------------
__global__ __launch_bounds__(256) void lnw_kernel(const float* __restrict__ x,
        const float* __restrict__ gamma, const float* __restrict__ beta,
        unsigned short* __restrict__ xn,
        const float* __restrict__ wq, const float* __restrict__ wk,
        const float* __restrict__ wv, const float* __restrict__ wo,
        unsigned short* __restrict__ wdst)
{
    if (blockIdx.x >= 2048) {
        int idx = blockIdx.x - 2048;
        int m = idx >> 6, sub = idx & 63;
        const float* src = (m == 0) ? wq : (m == 1) ? wk : (m == 2) ? wv : wo;
        unsigned short* d = wdst + (size_t)m * 262144;
        const f32x4* s4 = (const f32x4*)src;
        s16x4* d4 = (s16x4*)d;
#pragma unroll
        for (int i = 0; i < 4; ++i) {
            int e = sub * 1024 + i * 256 + threadIdx.x;
            f32x4 v = s4[e];
            s16x4 o;
            o[0] = f2bf(v[0]); o[1] = f2bf(v[1]); o[2] = f2bf(v[2]); o[3] = f2bf(v[3]);
            d4[e] = o;
        }
        return;
    }
    int t = threadIdx.x, w = t >> 6, lane = t & 63;
    int row = blockIdx.x * 4 + w;
    const float* xr = x + (size_t)row * 512 + lane * 8;
    f32x4 v0 = *(const f32x4*)xr;
    f32x4 v1 = *(const f32x4*)(xr + 4);
    float s = 0.f, s2 = 0.f;
#pragma unroll
    for (int i = 0; i < 4; ++i) { s += v0[i] + v1[i]; s2 += v0[i] * v0[i] + v1[i] * v1[i]; }
#pragma unroll
    for (int m = 1; m < 64; m <<= 1) { s += __shfl_xor(s, m); s2 += __shfl_xor(s2, m); }
    float mu = s * (1.f / 512.f);
    float var = s2 * (1.f / 512.f) - mu * mu;
    float rstd = rsqrtf(var + 1e-5f);
    f32x4 g0 = *(const f32x4*)(gamma + lane * 8);
    f32x4 g1 = *(const f32x4*)(gamma + lane * 8 + 4);
    f32x4 b0 = *(const f32x4*)(beta + lane * 8);
    f32x4 b1 = *(const f32x4*)(beta + lane * 8 + 4);
    s16x8 o;
#pragma unroll
    for (int i = 0; i < 4; ++i) {
        o[i]     = f2bf((v0[i] - mu) * rstd * g0[i] + b0[i]);
        o[i + 4] = f2bf((v1[i] - mu) * rstd * g1[i] + b1[i]);
    }
    *(s16x8*)(xn + (size_t)row * 512 + lane * 8) = o;
}

// ---------------- pipelined 128x128 GEMM core (BK=32, 3-buf, depth-2 prefetch) ----------------
#define GEMM_PIPE(APTR, BPTR, ACC) do { \
    int bc_ = 0, bs_ = 2; \
    STAGE(0, 0); STAGE(1, 1); \
    for (int it_ = 0; it_ < 16; ++it_) { \
        asm volatile("" ::: "memory"); \
        __builtin_amdgcn_s_barrier(); \
        if (it_ + 2 < 16) { \
            STAGE(it_ + 2, bs_); \
            asm volatile("s_waitcnt vmcnt(8)" ::: "memory"); \
        } else if (it_ + 1 < 16) { \
            asm volatile("s_waitcnt vmcnt(4)" ::: "memory"); \
        } else { \
            asm volatile("s_waitcnt vmcnt(0)" ::: "memory"); \
        } \
        __builtin_amdgcn_s_barrier(); \
        asm volatile("" ::: "memory"); \
        const char* Ab_ = (const char*)(APTR) + bc_ * 8192; \
        const char* Bb_ = (const char*)(BPTR) + bc_ * 8192; \
        s16x8 af_[4], bf_[4]; \
        _Pragma("unroll") \
        for (int i_ = 0; i_ < 4; ++i_) { \
            af_[i_] = *(const s16x8*)(Ab_ + (wm * 64 + i_ * 16 + l15) * 64 + swz); \
            bf_[i_] = *(const s16x8*)(Bb_ + (wn * 64 + i_ * 16 + l15) * 64 + swz); \
        } \
        __builtin_amdgcn_s_setprio(1); \
        _Pragma("unroll") \
        for (int i_ = 0; i_ < 4; ++i_) \
            _Pragma("unroll") \
            for (int j_ = 0; j_ < 4; ++j_) \
                ACC[i_][j_] = __builtin_amdgcn_mfma_f32_16x16x32_bf16(af_[i_], bf_[j_], ACC[i_][j_], 0, 0, 0); \
        __builtin_amdgcn_s_setprio(0); \
        bc_ = (bc_ == 2) ? 0 : bc_ + 1; \
        bs_ = (bs_ == 2) ? 0 : bs_ + 1; \
    } \
} while (0)

// ---------------- QKV projection GEMM ----------------
// z=0 -> q (b,h,s,dk) scaled 0.125*log2e ; z=1 -> K frag-major ; z=2 -> V frag-major
__global__ __launch_bounds__(256, 3) void qkv_kernel(const unsigned short* __restrict__ xn,
        const unsigned short* __restrict__ wbase,
        const float* __restrict__ bq, const float* __restrict__ bk, const float* __restrict__ bv,
        unsigned short* __restrict__ qo, unsigned short* __restrict__ kfm,
        unsigned short* __restrict__ vfm)
{
    __shared__ __align__(16) unsigned short As[3][128 * 32];
    __shared__ __align__(16) unsigned short Bs[3][128 * 32];
    int z = blockIdx.z;
    const unsigned short* W = wbase + (size_t)z * 262144;
    const float* bias = (z == 0) ? bq : (z == 1) ? bk : bv;

    int t = threadIdx.x, lane = t & 63, w = t >> 6;
    int g = lane >> 4, l15 = lane & 15;
    int wm = w >> 1, wn = w & 1;
    int mBase = blockIdx.x * 128, nBase = blockIdx.y * 128;

    int srow = t >> 2;
    int scol = ((t & 3) ^ ((t >> 2) & 3) ^ ((t >> 4) & 3)) * 8;
    const unsigned short* ag = xn + (size_t)(mBase + srow) * 512 + scol;
    const unsigned short* bg = W + (size_t)(nBase + srow) * 512 + scol;
    int swz = ((g ^ (l15 & 3) ^ ((l15 >> 2) & 3))) * 16;

    f32x4 acc[4][4] = {};

#define STAGE(it_, buf_) do { \
        int k0_ = (it_) * 32; \
        gl16(ag + k0_,          (char*)&As[buf_][0] + t * 16); \
        gl16(ag + 32768 + k0_,  (char*)&As[buf_][0] + t * 16 + 4096); \
        gl16(bg + k0_,          (char*)&Bs[buf_][0] + t * 16); \
        gl16(bg + 32768 + k0_,  (char*)&Bs[buf_][0] + t * 16 + 4096); \
    } while (0)

    GEMM_PIPE(&As[0][0], &Bs[0][0], acc);
#undef STAGE

#pragma unroll
    for (int i = 0; i < 4; ++i) {
        int row0 = mBase + wm * 64 + i * 16 + g * 4;
        int bb = row0 >> 11;
        int s0 = row0 & 2047;
#pragma unroll
        for (int j = 0; j < 4; ++j) {
            int col = nBase + wn * 64 + j * 16 + l15;
            float bia = bias[col];
            int h = col >> 6, dk = col & 63;
            int bh = bb * 8 + h;
            if (z == 0) {
                float sc = 0.18033688011112042f;   // 0.125*log2(e)
#pragma unroll
                for (int r = 0; r < 4; ++r)
                    qo[((size_t)bh * 2048 + (s0 + r)) * 64 + dk] = f2bf((acc[i][j][r] + bia) * sc);
            } else if (z == 1) {
                int ks = dk >> 5, gg = (dk >> 3) & 3, e = dk & 7;
                int tile = s0 >> 6, kf = (s0 >> 4) & 3, l0 = s0 & 15;
                size_t base = ((size_t)bh * 32 + tile) * 4096 + (kf * 2 + ks) * 512 + (gg * 16 + l0) * 8 + e;
#pragma unroll
                for (int r = 0; r < 4; ++r)
                    kfm[base + r * 8] = f2bf(acc[i][j][r] + bia);
            } else {
                int nf = dk >> 4, l0v = dk & 15;
                int tile = s0 >> 6, half = (s0 >> 5) & 1, gg = (s0 >> 3) & 3, e0 = s0 & 7;
                size_t base = ((size_t)bh * 32 + tile) * 4096 + (nf * 2 + half) * 512 + (gg * 16 + l0v) * 8 + e0;
                s16x4 pk;
#pragma unroll
                for (int r = 0; r < 4; ++r) pk[r] = f2bf(acc[i][j][r] + bia);
                *(s16x4*)(vfm + base) = pk;
            }
        }
    }
}

// ---------------- flash attention: K from global (frag-major), V-only LDS, 1 barrier/tile ----------------
// grid 1024, 256 thr = 4 waves x 32 q (128 q/block).
// Decode: h = lin&7 (fixed per XCD -> 2MB K/V L2-resident), b = (lin>>3)&3 (balanced per
// XCD/CU), split = (lin>>5)&1, qt = lin>>6. PARITY split: split s does tiles s, s+2, ...
// -> per-block tile count ~ntf/2 independent of len (fixed-max partials are linear).
__global__ __launch_bounds__(256, 4) void attn_kernel(const unsigned short* __restrict__ q,
        const unsigned short* __restrict__ kfm, const unsigned short* __restrict__ vfm,
        const int* __restrict__ lens, unsigned short* __restrict__ o_part, float* __restrict__ l_part)
{
    __shared__ __align__(16) unsigned short Vts[4][4096];   // [buf][8 frags][512 elems]

    int t = threadIdx.x, lane = t & 63, w = t >> 6;
    int g = lane >> 4, l15 = lane & 15;
    int lin = blockIdx.x;
    int h = lin & 7;
    int b = (lin >> 3) & 3;
    int split = (lin >> 5) & 1;
    int qt = lin >> 6;                 // 0..15
    int bh = b * 8 + h;
    int qb = qt * 128 + w * 32;
    int len = lens[b];
    int ntf = (len + 63) >> 6;
    int ntX = (ntf - split + 1) >> 1;  // tiles with parity `split` below ntf

    const unsigned short* kbh = kfm + (size_t)bh * 131072;
    const unsigned short* vbh = vfm + (size_t)bh * 131072;

    s16x8 qf_[2][2];
#pragma unroll
    for (int qf = 0; qf < 2; ++qf)
#pragma unroll
        for (int ks = 0; ks < 2; ++ks)
            qf_[qf][ks] = *(const s16x8*)(q + ((size_t)bh * 2048 + qb + qf * 16 + l15) * 64 + ks * 32 + g * 8);

    s16x8 ones;
#pragma unroll
    for (int i = 0; i < 8; ++i) ones[i] = (short)0x3F80;   // bf16 1.0

    f32x4 oacc[2][4] = {};   // [qf][nf]
    f32x4 sacc[2] = {};

#define STAGE_V(tile, buf) do { \
        const unsigned short* vp_ = vbh + (size_t)(tile) * 4096 + t * 8; \
        char* vld_ = (char*)&Vts[buf][0] + t * 16; \
        gl16(vp_, vld_); \
        gl16(vp_ + 2048, vld_ + 4096); \
    } while (0)

    STAGE_V(split, 0);
    if (ntX > 1) STAGE_V(split + 2, 1);

    for (int li = 0; li < ntX; ++li) {
        int tt = split + li * 2;
        int kb = tt << 6;

        // K fragments straight from global (coalesced 1KB per load, L2/L1-resident)
        const unsigned short* kt = kbh + (size_t)tt * 4096;
        s16x8 ka[4][2];
#pragma unroll
        for (int kf = 0; kf < 4; ++kf)
#pragma unroll
            for (int ks = 0; ks < 2; ++ks)
                ka[kf][ks] = *(const s16x8*)(kt + ((kf & 1) * 2 + ks) * 512 + (kf >> 1) * 2048 + lane * 8);

        if (li + 2 < ntX) {
            STAGE_V(tt + 4, (li + 2) & 3);
            asm volatile("s_waitcnt vmcnt(12)" ::: "memory");   // V(li) landed
        } else if (li + 1 < ntX) {
            asm volatile("s_waitcnt vmcnt(10)" ::: "memory");
        } else {
            asm volatile("s_waitcnt vmcnt(8)" ::: "memory");
        }
        __builtin_amdgcn_s_barrier();              // all waves certified V(li)
        asm volatile("" ::: "memory");

        const char* Vb = (const char*)&Vts[li & 3][0];

        // QK^T -> S^T: sa[kf2][qf]; k-row = kf2*16 + g*4 + r
        f32x4 sa[4][2] = {};
#pragma unroll
        for (int ks = 0; ks < 2; ++ks) {
            __builtin_amdgcn_s_setprio(1);
#pragma unroll
            for (int kf = 0; kf < 4; ++kf)
#pragma unroll
                for (int qf = 0; qf < 2; ++qf)
                    sa[kf][qf] = __builtin_amdgcn_mfma_f32_16x16x32_bf16(
                        ka[(kf >> 1) * 2 + (kf & 1)][ks], qf_[qf][ks], sa[kf][qf], 0, 0, 0);
            __builtin_amdgcn_s_setprio(0);
        }

        if (kb + 64 > len) {
            const float NEG = -__builtin_huge_valf();
#pragma unroll
            for (int kf = 0; kf < 4; ++kf)
#pragma unroll
                for (int r = 0; r < 4; ++r)
                    if (kb + kf * 16 + g * 4 + r >= len) { sa[kf][0][r] = NEG; sa[kf][1][r] = NEG; }
        }

        // two k-halves: exp2 (fixed-max, scale folded into q) -> permlane P -> PV
#pragma unroll
        for (int half = 0; half < 2; ++half) {
            s16x8 vbf[4];
#pragma unroll
            for (int nf = 0; nf < 4; ++nf)
                vbf[nf] = *(const s16x8*)(Vb + (nf * 2 + half) * 1024 + lane * 16);
            u32 pkd[2][2][2];
#pragma unroll
            for (int qf = 0; qf < 2; ++qf)
#pragma unroll
                for (int k2 = 0; k2 < 2; ++k2) {
                    int kf = half * 2 + k2;
#pragma unroll
                    for (int r = 0; r < 4; ++r)
                        sa[kf][qf][r] = __builtin_amdgcn_exp2f(sa[kf][qf][r]);
                    pkd[k2][qf][0] = cvtpk(sa[kf][qf][0], sa[kf][qf][1]);
                    pkd[k2][qf][1] = cvtpk(sa[kf][qf][2], sa[kf][qf][3]);
                }
            __builtin_amdgcn_s_setprio(1);
#pragma unroll
            for (int qf = 0; qf < 2; ++qf) {
                u32 a0 = pkd[0][qf][0], b0 = pkd[1][qf][0];
                u32 a1 = pkd[0][qf][1], b1 = pkd[1][qf][1];
                pl32swap(a0, b0); pl16swap(a0, b0);
                pl32swap(a1, b1); pl16swap(a1, b1);
                union { u32 d[4]; s16x8 v; } pf;
                pf.d[0] = a0; pf.d[1] = a1; pf.d[2] = b0; pf.d[3] = b1;
                sacc[qf] = __builtin_amdgcn_mfma_f32_16x16x32_bf16(pf.v, ones, sacc[qf], 0, 0, 0);
#pragma unroll
                for (int nf = 0; nf < 4; ++nf)
                    oacc[qf][nf] = __builtin_amdgcn_mfma_f32_16x16x32_bf16(pf.v, vbf[nf], oacc[qf][nf], 0, 0, 0);
            }
            __builtin_amdgcn_s_setprio(0);
        }
        asm volatile("" ::: "memory");
    }
#undef STAGE_V

    // write bf16 unnormalized O partial + fp32 l partial
    unsigned short* op = o_part + (size_t)split * (8192 * 512);
#pragma unroll
    for (int qf = 0; qf < 2; ++qf)
#pragma unroll
        for (int r = 0; r < 4; ++r) {
            int s = qb + qf * 16 + g * 4 + r;
#pragma unroll
            for (int nf = 0; nf < 4; ++nf)
                op[(size_t)(b * 2048 + s) * 512 + h * 64 + nf * 16 + l15] = f2bf(oacc[qf][nf][r]);
        }
    float* lp = l_part + split * 65536 + bh * 2048;
    if (l15 == 0) {
#pragma unroll
        for (int qf = 0; qf < 2; ++qf)
#pragma unroll
            for (int r = 0; r < 4; ++r)
                lp[qb + qf * 16 + g * 4 + r] = sacc[qf][r];
    }
}

// ---------------- combine: (O0+O1)/(l0+l1) -> bf16 ----------------
__global__ __launch_bounds__(256) void comb_kernel(const unsigned short* __restrict__ o_part,
        const float* __restrict__ l_part, unsigned short* __restrict__ A)
{
    int e0 = (blockIdx.x * 256 + threadIdx.x) * 8;
    int row = e0 >> 9, col0 = e0 & 511;
    int b = row >> 11, s = row & 2047, h = col0 >> 6;
    s16x8 u0 = *(const s16x8*)(o_part + (size_t)row * 512 + col0);
    s16x8 u1 = *(const s16x8*)(o_part + (size_t)(8192 + row) * 512 + col0);
    float l = l_part[(b * 8 + h) * 2048 + s] + l_part[65536 + (b * 8 + h) * 2048 + s];
    float inv = 1.f / l;
    s16x8 o;
#pragma unroll
    for (int i = 0; i < 8; ++i) {
        float f0 = __uint_as_float(((u32)(unsigned short)u0[i]) << 16);
        float f1 = __uint_as_float(((u32)(unsigned short)u1[i]) << 16);
        o[i] = f2bf((f0 + f1) * inv);
    }
    *(s16x8*)(A + (size_t)row * 512 + col0) = o;
}

// ---------------- output projection GEMM (fp32 out) ----------------
__global__ __launch_bounds__(256, 3) void oproj_kernel(const unsigned short* __restrict__ A,
        const unsigned short* __restrict__ W, const float* __restrict__ bo,
        float* __restrict__ out)
{
    __shared__ __align__(16) unsigned short As[3][128 * 32];
    __shared__ __align__(16) unsigned short Bs[3][128 * 32];
    int t = threadIdx.x, lane = t & 63, w = t >> 6;
    int g = lane >> 4, l15 = lane & 15;
    int wm = w >> 1, wn = w & 1;
    int mBase = blockIdx.x * 128, nBase = blockIdx.y * 128;

    int srow = t >> 2;
    int scol = ((t & 3) ^ ((t >> 2) & 3) ^ ((t >> 4) & 3)) * 8;
    const unsigned short* ag = A + (size_t)(mBase + srow) * 512 + scol;
    const unsigned short* bg = W + (size_t)(nBase + srow) * 512 + scol;
    int swz = ((g ^ (l15 & 3) ^ ((l15 >> 2) & 3))) * 16;

    f32x4 acc[4][4] = {};

#define STAGE(it_, buf_) do { \
        int k0_ = (it_) * 32; \
        gl16(ag + k0_,          (char*)&As[buf_][0] + t * 16); \
        gl16(ag + 32768 + k0_,  (char*)&As[buf_][0] + t * 16 + 4096); \
        gl16(bg + k0_,          (char*)&Bs[buf_][0] + t * 16); \
        gl16(bg + 32768 + k0_,  (char*)&Bs[buf_][0] + t * 16 + 4096); \
    } while (0)

    GEMM_PIPE(&As[0][0], &Bs[0][0], acc);
#undef STAGE

#pragma unroll
    for (int i = 0; i < 4; ++i) {
        int row0 = mBase + wm * 64 + i * 16 + g * 4;
#pragma unroll
        for (int j = 0; j < 4; ++j) {
            int col = nBase + wn * 64 + j * 16 + l15;
            float bia = bo[col];
#pragma unroll
            for (int r = 0; r < 4; ++r)
                out[(size_t)(row0 + r) * 512 + col] = acc[i][j][r] + bia;
        }
    }
}

extern "C" void kernel_launch(void* const* d_in, const int* in_sizes, int n_in,
                              void* d_out, int out_size, void* d_ws, size_t ws_size,
                              hipStream_t stream) {
    (void)in_sizes; (void)n_in; (void)out_size; (void)ws_size;
    const float* x     = (const float*)d_in[0];
    const int*   lens  = (const int*)d_in[1];
    // d_in[2] = pos_embed (unused by reference)
    const float* gamma = (const float*)d_in[3];
    const float* beta  = (const float*)d_in[4];
    const float* Wq = (const float*)d_in[5];
    const float* bq = (const float*)d_in[6];
    const float* Wk = (const float*)d_in[7];
    const float* bk = (const float*)d_in[8];
    const float* Wv = (const float*)d_in[9];
    const float* bv = (const float*)d_in[10];
    const float* Wo = (const float*)d_in[11];
    const float* bo = (const float*)d_in[12];

    char* ws = (char*)d_ws;
    unsigned short* wbf = (unsigned short*)(ws);                  // 0..2MB: 4x512x512 bf16
    unsigned short* xn  = (unsigned short*)(ws + (2ull  << 20));  // 2..10MB: LN out / attn-combined (oproj A)
    unsigned short* qb_ = (unsigned short*)(ws + (10ull << 20));  // (b,h,s,dk)
    unsigned short* kfm = (unsigned short*)(ws + (18ull << 20));  // K frag-major
    unsigned short* vfm = (unsigned short*)(ws + (26ull << 20));  // V frag-major
    unsigned short* o_part = (unsigned short*)(ws + (34ull << 20)); // 34..50MB: [2][8192][512] bf16
    float* l_part = (float*)(ws + (50ull << 20));                 // 50..50.5MB: [2][32][2048] f32
    float* out = (float*)d_out;

    lnw_kernel<<<2304, 256, 0, stream>>>(x, gamma, beta, xn, Wq, Wk, Wv, Wo, wbf);
    qkv_kernel<<<dim3(64, 4, 3), 256, 0, stream>>>(xn, wbf, bq, bk, bv, qb_, kfm, vfm);
    attn_kernel<<<1024, 256, 0, stream>>>(qb_, kfm, vfm, lens, o_part, l_part);
    comb_kernel<<<2048, 256, 0, stream>>>(o_part, l_part, xn);
    oproj_kernel<<<dim3(64, 4), 256, 0, stream>>>(xn, wbf + 3 * 262144, bo, out);
}